// Round 4
// baseline (1250.416 us; speedup 1.0000x reference)
//
#include <hip/hip_runtime.h>
#include <hip/hip_bf16.h>

#define NN 100000
#define EE 1600000
#define DOUT 40
#define LN_EPS 1e-5f
#define NB 391  // (NN+255)/256

// ---------------------------------------------------------------- bf16 pack/unpack (RNE)
__device__ __forceinline__ float blo(unsigned u) { return __uint_as_float(u << 16); }
__device__ __forceinline__ float bhi(unsigned u) { return __uint_as_float(u & 0xffff0000u); }
__device__ __forceinline__ unsigned bpack(float lo, float hi) {
    unsigned a = __float_as_uint(lo);
    unsigned b = __float_as_uint(hi);
    a = (a + 0x7fffu + ((a >> 16) & 1u)) >> 16;
    b = (b + 0x7fffu + ((b >> 16) & 1u)) & 0xffff0000u;
    return (a & 0xffffu) | b;
}

// ---------------------------------------------------------------- CSR build
__global__ void hist_k(const int* __restrict__ dst, int* __restrict__ degI) {
    int e = blockIdx.x * 256 + threadIdx.x;
    if (e < EE) atomicAdd(&degI[dst[e]], 1);
}

__global__ void dinv_k(const int* __restrict__ degI, float* __restrict__ dinv) {
    int n = blockIdx.x * 256 + threadIdx.x;
    if (n < NN) dinv[n] = rsqrtf((float)degI[n] + 1.0f);
}

__global__ void scan1_k(const int* __restrict__ degI, int* __restrict__ cursor,
                        int* __restrict__ bsum) {
    __shared__ int s[256];
    int tid = threadIdx.x;
    int i = blockIdx.x * 256 + tid;
    int v = (i < NN) ? degI[i] : 0;
    s[tid] = v;
    __syncthreads();
    for (int off = 1; off < 256; off <<= 1) {
        int t = (tid >= off) ? s[tid - off] : 0;
        __syncthreads();
        s[tid] += t;
        __syncthreads();
    }
    if (i < NN) cursor[i] = s[tid] - v;
    if (tid == 255) bsum[blockIdx.x] = s[255];
}

__global__ void scan2_k(int* __restrict__ bsum) {
    __shared__ int s[512];
    int tid = threadIdx.x;
    int v = (tid < NB) ? bsum[tid] : 0;
    s[tid] = v;
    __syncthreads();
    for (int off = 1; off < 512; off <<= 1) {
        int t = (tid >= off) ? s[tid - off] : 0;
        __syncthreads();
        s[tid] += t;
        __syncthreads();
    }
    if (tid < NB) bsum[tid] = s[tid] - v;
}

__global__ void scan3_k(int* __restrict__ cursor, const int* __restrict__ bsum) {
    int i = blockIdx.x * 256 + threadIdx.x;
    if (i < NN) cursor[i] += bsum[blockIdx.x];
}

__global__ void reorder_k(const int* __restrict__ src, const int* __restrict__ dst,
                          int* __restrict__ cursor, int* __restrict__ csrSrc) {
    int e = blockIdx.x * 256 + threadIdx.x;
    if (e < EE) {
        int pos = atomicAdd(&cursor[dst[e]], 1);
        csrSrc[pos] = src[e];
    }
}

// ---------------------------------------------------------------- GEMM  [N,K]@[K,64] -> H' = (xW)*dinv, bf16 packed
template <int K>
__global__ void gemm_k(const float* __restrict__ X, const float* __restrict__ W,
                       const float* __restrict__ dinv, unsigned* __restrict__ H) {
    __shared__ float sW[K * 64];
    int tid = threadIdx.x;
    for (int i = tid; i < K * 64; i += 256) sW[i] = W[i];
    __syncthreads();
    int w = tid >> 6, lane = tid & 63;
    for (int base = blockIdx.x * 4; base < NN; base += gridDim.x * 4) {
        int node = base + w;
        if (node < NN) {
            float xv[K / 64];
#pragma unroll
            for (int j = 0; j < K / 64; ++j) xv[j] = X[(long)node * K + j * 64 + lane];
            float acc = 0.f;
#pragma unroll
            for (int j = 0; j < K / 64; ++j) {
#pragma unroll
                for (int k = 0; k < 64; ++k) {
                    float xk = __shfl(xv[j], k);
                    acc = fmaf(xk, sW[(j * 64 + k) * 64 + lane], acc);
                }
            }
            acc *= dinv[node];
            float v0 = __shfl(acc, (lane & 31) * 2);
            float v1 = __shfl(acc, (lane & 31) * 2 + 1);
            if (lane < 32) H[node * 32 + lane] = bpack(v0, v1);
        }
    }
}

// ---------------------------------------------------------------- gather core
// lane = g*8+f: g = edge slot (0..7), f = feature-octet (0..7). 2-deep unroll
// => 16 outstanding 128B gathers per wave, 16 edges/iter.
__device__ __forceinline__ void acc8(float* a, const uint4 q) {
    a[0] += blo(q.x); a[1] += bhi(q.x);
    a[2] += blo(q.y); a[3] += bhi(q.y);
    a[4] += blo(q.z); a[5] += bhi(q.z);
    a[6] += blo(q.w); a[7] += bhi(q.w);
}

__device__ __forceinline__ void gather_node(int node, int g, int f,
                                            const int* __restrict__ cursor,
                                            const int* __restrict__ degI,
                                            const int* __restrict__ csrSrc,
                                            const uint4* __restrict__ H4, float* a) {
    int end = cursor[node];
    int start = end - degI[node];
    float b[8] = {0, 0, 0, 0, 0, 0, 0, 0};
    int e = start + g;
    for (; e + 8 < end; e += 16) {
        int s0 = csrSrc[e];
        int s1 = csrSrc[e + 8];
        uint4 q0 = H4[(long)s0 * 8 + f];
        uint4 q1 = H4[(long)s1 * 8 + f];
        acc8(a, q0);
        acc8(b, q1);
    }
    if (e < end) {
        uint4 q0 = H4[(long)csrSrc[e] * 8 + f];
        acc8(a, q0);
    }
#pragma unroll
    for (int j = 0; j < 8; ++j) a[j] += b[j];
    // reduce across the 8 edge slots (xor g bits): all lanes end with full sum
#pragma unroll
    for (int j = 0; j < 8; ++j) {
        a[j] += __shfl_xor(a[j], 8);
        a[j] += __shfl_xor(a[j], 16);
        a[j] += __shfl_xor(a[j], 32);
    }
}

// ---------------------------------------------------------------- agg + bias + relu + LN  (f32 out)
__global__ void agg_k(const int* __restrict__ cursor, const int* __restrict__ degI,
                      const int* __restrict__ csrSrc, const float* __restrict__ dinv,
                      const uint4* __restrict__ H4, const float* __restrict__ bias,
                      const float* __restrict__ gam, const float* __restrict__ bet,
                      float* __restrict__ OUT, int doLN) {
    int tid = threadIdx.x;
    int w = tid >> 6, lane = tid & 63;
    int g = lane >> 3, f = lane & 7;
    int node = blockIdx.x * 4 + w;  // grid exactly NN/4
    float a[8];
#pragma unroll
    for (int j = 0; j < 8; ++j) a[j] = 0.f;
    gather_node(node, g, f, cursor, degI, csrSrc, H4, a);
    float di = dinv[node];
    uint4 qs = H4[(long)node * 8 + f];
    float sf[8] = {blo(qs.x), bhi(qs.x), blo(qs.y), bhi(qs.y),
                   blo(qs.z), bhi(qs.z), blo(qs.w), bhi(qs.w)};
    float4 bA = ((const float4*)bias)[f * 2], bB = ((const float4*)bias)[f * 2 + 1];
    float bb[8] = {bA.x, bA.y, bA.z, bA.w, bB.x, bB.y, bB.z, bB.w};
    float v[8];
#pragma unroll
    for (int j = 0; j < 8; ++j) v[j] = fmaxf((a[j] + sf[j]) * di + bb[j], 0.f);
    if (doLN) {
        float s = 0.f;
#pragma unroll
        for (int j = 0; j < 8; ++j) s += v[j];
        s += __shfl_xor(s, 1); s += __shfl_xor(s, 2); s += __shfl_xor(s, 4);
        float mu = s * (1.f / 64.f);
        float vs = 0.f;
#pragma unroll
        for (int j = 0; j < 8; ++j) { v[j] -= mu; vs += v[j] * v[j]; }
        vs += __shfl_xor(vs, 1); vs += __shfl_xor(vs, 2); vs += __shfl_xor(vs, 4);
        float inv = rsqrtf(vs * (1.f / 64.f) + LN_EPS);
        float4 gA = ((const float4*)gam)[f * 2], gB = ((const float4*)gam)[f * 2 + 1];
        float4 tA = ((const float4*)bet)[f * 2], tB = ((const float4*)bet)[f * 2 + 1];
        float gg[8] = {gA.x, gA.y, gA.z, gA.w, gB.x, gB.y, gB.z, gB.w};
        float tt[8] = {tA.x, tA.y, tA.z, tA.w, tB.x, tB.y, tB.z, tB.w};
#pragma unroll
        for (int j = 0; j < 8; ++j) v[j] = v[j] * inv * gg[j] + tt[j];
    }
    if (g == 0) {
        float4* O = (float4*)OUT;
        O[(long)node * 16 + f * 2]     = make_float4(v[0], v[1], v[2], v[3]);
        O[(long)node * 16 + f * 2 + 1] = make_float4(v[4], v[5], v[6], v[7]);
    }
}

// ---------------------------------------------------------------- agg + relu + MLP head (grid-stride, shfl layout)
__global__ void agg_mlp_k(const int* __restrict__ cursor, const int* __restrict__ degI,
                          const int* __restrict__ csrSrc, const float* __restrict__ dinv,
                          const uint4* __restrict__ H4, const float* __restrict__ bias,
                          const float* __restrict__ W0, const float* __restrict__ b0,
                          const float* __restrict__ W1, const float* __restrict__ b1,
                          float* __restrict__ OUT) {
    __shared__ float sW0[64 * 64];
    __shared__ float sW1[64 * DOUT];
    int tid = threadIdx.x;
    for (int i = tid; i < 64 * 64; i += 256) sW0[i] = W0[i];
    for (int i = tid; i < 64 * DOUT; i += 256) sW1[i] = W1[i];
    __syncthreads();
    int w = tid >> 6, lane = tid & 63;
    int g = lane >> 3, f = lane & 7;
    for (int node = blockIdx.x * 4 + w; node < NN; node += gridDim.x * 4) {
        float a[8];
#pragma unroll
        for (int j = 0; j < 8; ++j) a[j] = 0.f;
        gather_node(node, g, f, cursor, degI, csrSrc, H4, a);
        float di = dinv[node];
        uint4 qs = H4[(long)node * 8 + f];
        float sf[8] = {blo(qs.x), bhi(qs.x), blo(qs.y), bhi(qs.y),
                       blo(qs.z), bhi(qs.z), blo(qs.w), bhi(qs.w)};
        float4 bA = ((const float4*)bias)[f * 2], bB = ((const float4*)bias)[f * 2 + 1];
        float bb[8] = {bA.x, bA.y, bA.z, bA.w, bB.x, bB.y, bB.z, bB.w};
        float v[8];
#pragma unroll
        for (int j = 0; j < 8; ++j) v[j] = fmaxf((a[j] + sf[j]) * di + bb[j], 0.f);
        // every lane with the same f holds identical v[]; h[k=f'*8+j'] = shfl(v[j'], f')
        float t = b0[lane];
#pragma unroll
        for (int k = 0; k < 64; ++k)
            t = fmaf(__shfl(v[k & 7], k >> 3), sW0[k * 64 + lane], t);
        int li = (lane < DOUT) ? lane : 0;
        float o = b1[li];
#pragma unroll
        for (int k = 0; k < 64; ++k) o = fmaf(__shfl(t, k), sW1[k * DOUT + li], o);
        if (lane < DOUT) OUT[(long)node * DOUT + lane] = o;
    }
}

// ----------------------------------------------------------------
extern "C" void kernel_launch(void* const* d_in, const int* in_sizes, int n_in,
                              void* d_out, int out_size, void* d_ws, size_t ws_size,
                              hipStream_t stream) {
    const float* x    = (const float*)d_in[0];
    const int*   ei   = (const int*)d_in[1];
    const int*   srcI = ei;
    const int*   dstI = ei + EE;
    const float* W0   = (const float*)d_in[2];
    const float* b0   = (const float*)d_in[3];
    const float* W1   = (const float*)d_in[4];
    const float* b1   = (const float*)d_in[5];
    const float* W2   = (const float*)d_in[6];
    const float* b2   = (const float*)d_in[7];
    const float* ln0g = (const float*)d_in[8];
    const float* ln0b = (const float*)d_in[9];
    const float* ln1g = (const float*)d_in[10];
    const float* ln1b = (const float*)d_in[11];
    const float* mpW0 = (const float*)d_in[12];
    const float* mpb0 = (const float*)d_in[13];
    const float* mpW1 = (const float*)d_in[14];
    const float* mpb1 = (const float*)d_in[15];
    float* out = (float*)d_out;

    char* ws = (char*)d_ws;
    float*    dinv   = (float*)   (ws + 0);
    int*      degI   = (int*)     (ws + 512l * 1024);
    int*      cursor = (int*)     (ws + 1024l * 1024);
    int*      bsum   = (int*)     (ws + 1536l * 1024);
    int*      csrSrc = (int*)     (ws + 2048l * 1024);          // 6.4 MB
    unsigned* bufA   = (unsigned*)(ws + 9l * 1024 * 1024);      // bf16 H'  12.8 MB
    float*    bufB   = (float*)   (ws + 23l * 1024 * 1024);     // f32 hidden 25.6 MB

    const int edgeBlocks = (EE + 255) / 256;
    const int aggBlocks  = NN / 4;  // 25000 exact

    hipMemsetAsync(degI, 0, NN * sizeof(int), stream);
    hist_k<<<edgeBlocks, 256, 0, stream>>>(dstI, degI);
    dinv_k<<<NB, 256, 0, stream>>>(degI, dinv);
    scan1_k<<<NB, 256, 0, stream>>>(degI, cursor, bsum);
    scan2_k<<<1, 512, 0, stream>>>(bsum);
    scan3_k<<<NB, 256, 0, stream>>>(cursor, bsum);
    reorder_k<<<edgeBlocks, 256, 0, stream>>>(srcI, dstI, cursor, csrSrc);

    // layer 0
    gemm_k<128><<<2048, 256, 0, stream>>>(x, W0, dinv, bufA);
    agg_k<<<aggBlocks, 256, 0, stream>>>(cursor, degI, csrSrc, dinv, (const uint4*)bufA,
                                         b0, ln0g, ln0b, bufB, 1);
    // layer 1
    gemm_k<64><<<2048, 256, 0, stream>>>(bufB, W1, dinv, bufA);
    agg_k<<<aggBlocks, 256, 0, stream>>>(cursor, degI, csrSrc, dinv, (const uint4*)bufA,
                                         b1, ln1g, ln1b, bufB, 1);
    // layer 2 + MLP head
    gemm_k<64><<<2048, 256, 0, stream>>>(bufB, W2, dinv, bufA);
    agg_mlp_k<<<2048, 256, 0, stream>>>(cursor, degI, csrSrc, dinv, (const uint4*)bufA,
                                        b2, mpW0, mpb0, mpW1, mpb1, out);
}

// Round 5
// 1224.846 us; speedup vs baseline: 1.0209x; 1.0209x over previous
//
#include <hip/hip_runtime.h>
#include <hip/hip_bf16.h>

#define NN 100000
#define EE 1600000
#define DOUT 40
#define LN_EPS 1e-5f
#define NB 391  // (NN+255)/256

typedef float f8 __attribute__((ext_vector_type(8)));

// ---------------------------------------------------------------- bf16 pack/unpack (RNE)
__device__ __forceinline__ float blo(unsigned u) { return __uint_as_float(u << 16); }
__device__ __forceinline__ float bhi(unsigned u) { return __uint_as_float(u & 0xffff0000u); }
__device__ __forceinline__ unsigned bpack(float lo, float hi) {
    unsigned a = __float_as_uint(lo);
    unsigned b = __float_as_uint(hi);
    a = (a + 0x7fffu + ((a >> 16) & 1u)) >> 16;
    b = (b + 0x7fffu + ((b >> 16) & 1u)) & 0xffff0000u;
    return (a & 0xffffu) | b;
}

// unpack 8 bf16 (uint4) -> f8, value-returning (register-resident)
__device__ __forceinline__ f8 unp(uint4 q) {
    f8 r;
    r[0] = blo(q.x); r[1] = bhi(q.x);
    r[2] = blo(q.y); r[3] = bhi(q.y);
    r[4] = blo(q.z); r[5] = bhi(q.z);
    r[6] = blo(q.w); r[7] = bhi(q.w);
    return r;
}

// ---------------------------------------------------------------- CSR build
__global__ void hist_k(const int* __restrict__ dst, int* __restrict__ degI) {
    int e = blockIdx.x * 256 + threadIdx.x;
    if (e < EE) atomicAdd(&degI[dst[e]], 1);
}

__global__ void dinv_k(const int* __restrict__ degI, float* __restrict__ dinv) {
    int n = blockIdx.x * 256 + threadIdx.x;
    if (n < NN) dinv[n] = rsqrtf((float)degI[n] + 1.0f);
}

__global__ void scan1_k(const int* __restrict__ degI, int* __restrict__ cursor,
                        int* __restrict__ bsum) {
    __shared__ int s[256];
    int tid = threadIdx.x;
    int i = blockIdx.x * 256 + tid;
    int v = (i < NN) ? degI[i] : 0;
    s[tid] = v;
    __syncthreads();
    for (int off = 1; off < 256; off <<= 1) {
        int t = (tid >= off) ? s[tid - off] : 0;
        __syncthreads();
        s[tid] += t;
        __syncthreads();
    }
    if (i < NN) cursor[i] = s[tid] - v;
    if (tid == 255) bsum[blockIdx.x] = s[255];
}

__global__ void scan2_k(int* __restrict__ bsum) {
    __shared__ int s[512];
    int tid = threadIdx.x;
    int v = (tid < NB) ? bsum[tid] : 0;
    s[tid] = v;
    __syncthreads();
    for (int off = 1; off < 512; off <<= 1) {
        int t = (tid >= off) ? s[tid - off] : 0;
        __syncthreads();
        s[tid] += t;
        __syncthreads();
    }
    if (tid < NB) bsum[tid] = s[tid] - v;
}

__global__ void scan3_k(int* __restrict__ cursor, const int* __restrict__ bsum) {
    int i = blockIdx.x * 256 + threadIdx.x;
    if (i < NN) cursor[i] += bsum[blockIdx.x];
}

__global__ void reorder_k(const int* __restrict__ src, const int* __restrict__ dst,
                          int* __restrict__ cursor, int* __restrict__ csrSrc) {
    int e = blockIdx.x * 256 + threadIdx.x;
    if (e < EE) {
        int pos = atomicAdd(&cursor[dst[e]], 1);
        csrSrc[pos] = src[e];
    }
}

// ---------------------------------------------------------------- GEMM  [N,K]@[K,64] -> H' = (xW)*dinv, bf16 packed
template <int K>
__global__ void gemm_k(const float* __restrict__ X, const float* __restrict__ W,
                       const float* __restrict__ dinv, unsigned* __restrict__ H) {
    __shared__ float sW[K * 64];
    int tid = threadIdx.x;
    for (int i = tid; i < K * 64; i += 256) sW[i] = W[i];
    __syncthreads();
    int w = tid >> 6, lane = tid & 63;
    for (int base = blockIdx.x * 4; base < NN; base += gridDim.x * 4) {
        int node = base + w;
        if (node < NN) {
            float xv0 = X[(long)node * K + lane];
            float xv1 = (K == 128) ? X[(long)node * K + 64 + lane] : 0.f;
            float acc = 0.f;
#pragma unroll
            for (int k = 0; k < 64; ++k) {
                float xk = __shfl(xv0, k);
                acc = fmaf(xk, sW[k * 64 + lane], acc);
            }
            if (K == 128) {
#pragma unroll
                for (int k = 0; k < 64; ++k) {
                    float xk = __shfl(xv1, k);
                    acc = fmaf(xk, sW[(64 + k) * 64 + lane], acc);
                }
            }
            acc *= dinv[node];
            float v0 = __shfl(acc, (lane & 31) * 2);
            float v1 = __shfl(acc, (lane & 31) * 2 + 1);
            if (lane < 32) H[node * 32 + lane] = bpack(v0, v1);
        }
    }
}

// ---------------------------------------------------------------- agg + bias + relu + LN  (f32 out)
// lane = g*8+f: g = edge slot (0..7), f = feature-octet (0..7); 2-deep unroll
// => 16 outstanding 128B gathers per wave. All state in ext-vector regs.
__global__ void agg_k(const int* __restrict__ cursor, const int* __restrict__ degI,
                      const int* __restrict__ csrSrc, const float* __restrict__ dinv,
                      const uint4* __restrict__ H4, const float* __restrict__ bias,
                      const float* __restrict__ gam, const float* __restrict__ bet,
                      float* __restrict__ OUT, int doLN) {
    int tid = threadIdx.x;
    int w = tid >> 6, lane = tid & 63;
    int g = lane >> 3, f = lane & 7;
    int node = blockIdx.x * 4 + w;  // grid exactly NN/4
    int end = cursor[node];
    int start = end - degI[node];
    f8 a = {0, 0, 0, 0, 0, 0, 0, 0};
    f8 b = {0, 0, 0, 0, 0, 0, 0, 0};
    int e = start + g;
    for (; e + 8 < end; e += 16) {
        int s0 = csrSrc[e];
        int s1 = csrSrc[e + 8];
        uint4 q0 = H4[(long)s0 * 8 + f];
        uint4 q1 = H4[(long)s1 * 8 + f];
        a += unp(q0);
        b += unp(q1);
    }
    if (e < end) a += unp(H4[(long)csrSrc[e] * 8 + f]);
    a += b;
#pragma unroll
    for (int j = 0; j < 8; ++j) {
        float t = a[j];
        t += __shfl_xor(t, 8);
        t += __shfl_xor(t, 16);
        t += __shfl_xor(t, 32);
        a[j] = t;
    }
    float di = dinv[node];
    f8 self = unp(H4[(long)node * 8 + f]);
    f8 bb = ((const f8*)bias)[f];
    f8 v;
#pragma unroll
    for (int j = 0; j < 8; ++j) v[j] = fmaxf((a[j] + self[j]) * di + bb[j], 0.f);
    if (doLN) {
        float s = 0.f;
#pragma unroll
        for (int j = 0; j < 8; ++j) s += v[j];
        s += __shfl_xor(s, 1); s += __shfl_xor(s, 2); s += __shfl_xor(s, 4);
        float mu = s * (1.f / 64.f);
        float vs = 0.f;
#pragma unroll
        for (int j = 0; j < 8; ++j) {
            v[j] -= mu;
            vs += v[j] * v[j];
        }
        vs += __shfl_xor(vs, 1); vs += __shfl_xor(vs, 2); vs += __shfl_xor(vs, 4);
        float inv = rsqrtf(vs * (1.f / 64.f) + LN_EPS);
        f8 gg = ((const f8*)gam)[f];
        f8 tt = ((const f8*)bet)[f];
#pragma unroll
        for (int j = 0; j < 8; ++j) v[j] = v[j] * inv * gg[j] + tt[j];
    }
    if (g == 0) ((f8*)OUT)[(long)node * 8 + f] = v;
}

// ---------------------------------------------------------------- agg + relu + MLP head (grid-stride, shfl layout)
__global__ void agg_mlp_k(const int* __restrict__ cursor, const int* __restrict__ degI,
                          const int* __restrict__ csrSrc, const float* __restrict__ dinv,
                          const uint4* __restrict__ H4, const float* __restrict__ bias,
                          const float* __restrict__ W0, const float* __restrict__ b0,
                          const float* __restrict__ W1, const float* __restrict__ b1,
                          float* __restrict__ OUT) {
    __shared__ float sW0[64 * 64];
    __shared__ float sW1[64 * DOUT];
    int tid = threadIdx.x;
    for (int i = tid; i < 64 * 64; i += 256) sW0[i] = W0[i];
    for (int i = tid; i < 64 * DOUT; i += 256) sW1[i] = W1[i];
    __syncthreads();
    int w = tid >> 6, lane = tid & 63;
    int g = lane >> 3, f = lane & 7;
    for (int node = blockIdx.x * 4 + w; node < NN; node += gridDim.x * 4) {
        int end = cursor[node];
        int start = end - degI[node];
        f8 a = {0, 0, 0, 0, 0, 0, 0, 0};
        f8 b = {0, 0, 0, 0, 0, 0, 0, 0};
        int e = start + g;
        for (; e + 8 < end; e += 16) {
            int s0 = csrSrc[e];
            int s1 = csrSrc[e + 8];
            uint4 q0 = H4[(long)s0 * 8 + f];
            uint4 q1 = H4[(long)s1 * 8 + f];
            a += unp(q0);
            b += unp(q1);
        }
        if (e < end) a += unp(H4[(long)csrSrc[e] * 8 + f]);
        a += b;
#pragma unroll
        for (int j = 0; j < 8; ++j) {
            float t = a[j];
            t += __shfl_xor(t, 8);
            t += __shfl_xor(t, 16);
            t += __shfl_xor(t, 32);
            a[j] = t;
        }
        float di = dinv[node];
        f8 self = unp(H4[(long)node * 8 + f]);
        f8 bb = ((const f8*)bias)[f];
        f8 v;
#pragma unroll
        for (int j = 0; j < 8; ++j) v[j] = fmaxf((a[j] + self[j]) * di + bb[j], 0.f);
        // h[k = fp*8 + j] = shfl(v[j], fp): all component indices are literals
        float t = b0[lane];
#pragma unroll
        for (int fp = 0; fp < 8; ++fp) {
#pragma unroll
            for (int j = 0; j < 8; ++j) {
                float hk = __shfl(v[j], fp);
                t = fmaf(hk, sW0[(fp * 8 + j) * 64 + lane], t);
            }
        }
        int li = (lane < DOUT) ? lane : 0;
        float o = b1[li];
#pragma unroll
        for (int k = 0; k < 64; ++k) o = fmaf(__shfl(t, k), sW1[k * DOUT + li], o);
        if (lane < DOUT) OUT[(long)node * DOUT + lane] = o;
    }
}

// ----------------------------------------------------------------
extern "C" void kernel_launch(void* const* d_in, const int* in_sizes, int n_in,
                              void* d_out, int out_size, void* d_ws, size_t ws_size,
                              hipStream_t stream) {
    const float* x    = (const float*)d_in[0];
    const int*   ei   = (const int*)d_in[1];
    const int*   srcI = ei;
    const int*   dstI = ei + EE;
    const float* W0   = (const float*)d_in[2];
    const float* b0   = (const float*)d_in[3];
    const float* W1   = (const float*)d_in[4];
    const float* b1   = (const float*)d_in[5];
    const float* W2   = (const float*)d_in[6];
    const float* b2   = (const float*)d_in[7];
    const float* ln0g = (const float*)d_in[8];
    const float* ln0b = (const float*)d_in[9];
    const float* ln1g = (const float*)d_in[10];
    const float* ln1b = (const float*)d_in[11];
    const float* mpW0 = (const float*)d_in[12];
    const float* mpb0 = (const float*)d_in[13];
    const float* mpW1 = (const float*)d_in[14];
    const float* mpb1 = (const float*)d_in[15];
    float* out = (float*)d_out;

    char* ws = (char*)d_ws;
    float*    dinv   = (float*)   (ws + 0);
    int*      degI   = (int*)     (ws + 512l * 1024);
    int*      cursor = (int*)     (ws + 1024l * 1024);
    int*      bsum   = (int*)     (ws + 1536l * 1024);
    int*      csrSrc = (int*)     (ws + 2048l * 1024);          // 6.4 MB
    unsigned* bufA   = (unsigned*)(ws + 9l * 1024 * 1024);      // bf16 H'  12.8 MB
    float*    bufB   = (float*)   (ws + 23l * 1024 * 1024);     // f32 hidden 25.6 MB

    const int edgeBlocks = (EE + 255) / 256;
    const int aggBlocks  = NN / 4;  // 25000 exact

    hipMemsetAsync(degI, 0, NN * sizeof(int), stream);
    hist_k<<<edgeBlocks, 256, 0, stream>>>(dstI, degI);
    dinv_k<<<NB, 256, 0, stream>>>(degI, dinv);
    scan1_k<<<NB, 256, 0, stream>>>(degI, cursor, bsum);
    scan2_k<<<1, 512, 0, stream>>>(bsum);
    scan3_k<<<NB, 256, 0, stream>>>(cursor, bsum);
    reorder_k<<<edgeBlocks, 256, 0, stream>>>(srcI, dstI, cursor, csrSrc);

    // layer 0
    gemm_k<128><<<2048, 256, 0, stream>>>(x, W0, dinv, bufA);
    agg_k<<<aggBlocks, 256, 0, stream>>>(cursor, degI, csrSrc, dinv, (const uint4*)bufA,
                                         b0, ln0g, ln0b, bufB, 1);
    // layer 1
    gemm_k<64><<<2048, 256, 0, stream>>>(bufB, W1, dinv, bufA);
    agg_k<<<aggBlocks, 256, 0, stream>>>(cursor, degI, csrSrc, dinv, (const uint4*)bufA,
                                         b1, ln1g, ln1b, bufB, 1);
    // layer 2 + MLP head
    gemm_k<64><<<2048, 256, 0, stream>>>(bufB, W2, dinv, bufA);
    agg_mlp_k<<<2048, 256, 0, stream>>>(cursor, degI, csrSrc, dinv, (const uint4*)bufA,
                                        b2, mpW0, mpb0, mpW1, mpb1, out);
}